// Round 6
// baseline (263.167 us; speedup 1.0000x reference)
//
#include <hip/hip_runtime.h>

// CARAFE++ downsample: B=8, C=128, H=W=160, stride 2 -> HD=WD=80
#define B   8
#define C   128
#define H   160
#define W   160
#define HW  (H*W)       // 25600
#define CM  16
#define KC  25
#define HD  80
#define WD  80
#define HWD (HD*WD)     // 6400

// comp LDS index with XOR swizzle (breaks the col-stride-2 -> bank-0 pattern;
// XOR value is a multiple of 4 so float4 runs stay contiguous & 16B aligned)
__device__ __forceinline__ int cidx(int row, int col, int ci) {
    return (row * 17 + col) * CM + (ci ^ ((col & 6) << 1));
}

// ---- fused stage 1+2: 1x1 conv 128->16 (LDS tile) + 3x3 s2 conv + softmax ----
// One block per 8x8 output tile: comp patch = 17x17 positions x 16 ch in LDS.
// Pass1: 256 threads compute comp for 289 clamped positions (zeros at OOB ->
// reference zero-padding). Pass2: 4 waves x 4ci each, 64 outputs, we[] indices
// wave-uniform -> s_loads. Pass3: LDS reduce + softmax + ker store.
__global__ __launch_bounds__(256) void encode_fused_k(const float* __restrict__ x,
                                                      const float* __restrict__ wc,
                                                      const float* __restrict__ we,
                                                      float* __restrict__ ker) {
    __shared__ float comp_lds[17 * 17 * CM];        // 18.5 KB
    __shared__ float part[4][KC][64];               // 25.6 KB

    int bid = blockIdx.x;                           // 0..799
    int tw  = bid % 10;                             // wd tile
    int t2  = bid / 10;
    int th  = t2 % 10;                              // hd tile
    int b   = t2 / 10;
    int hd0 = th * 8, wd0 = tw * 8;
    int R0  = 2 * hd0 - 1, C0 = 2 * wd0 - 1;        // comp patch origin

    const float* xb = x + (size_t)b * C * HW;

    // ---- pass 1: comp patch (289 positions) ----
    for (int p = threadIdx.x; p < 289; p += 256) {
        int pr = p / 17, pc = p % 17;
        int r  = R0 + pr, c = C0 + pc;
        bool oob = ((unsigned)r >= H) | ((unsigned)c >= W);
        int  ra  = min(max(r, 0), H - 1) * W + min(max(c, 0), W - 1);
        float acc[CM];
#pragma unroll
        for (int co = 0; co < CM; ++co) acc[co] = 0.f;
        for (int ci0 = 0; ci0 < C; ci0 += 8) {
            float v[8];
#pragma unroll
            for (int u = 0; u < 8; ++u)
                v[u] = xb[(size_t)(ci0 + u) * HW + ra];
#pragma unroll
            for (int u = 0; u < 8; ++u)
#pragma unroll
                for (int co = 0; co < CM; ++co)
                    acc[co] = fmaf(v[u], wc[co * C + ci0 + u], acc[co]);
        }
        float sc = oob ? 0.f : 1.f;                 // zero-pad semantics
#pragma unroll
        for (int co4 = 0; co4 < CM; co4 += 4) {
            float4 q = make_float4(acc[co4] * sc, acc[co4 + 1] * sc,
                                   acc[co4 + 2] * sc, acc[co4 + 3] * sc);
            *reinterpret_cast<float4*>(&comp_lds[cidx(pr, pc, co4)]) = q;
        }
    }
    __syncthreads();

    // ---- pass 2: encoder conv, 4 waves x 4 input channels ----
    int o   = threadIdx.x & 63;                     // output in tile
    int cig = threadIdx.x >> 6;                     // wave id -> ci group (uniform)
    int lhd = o >> 3, lwd = o & 7;
    float acc[KC];
#pragma unroll
    for (int ko = 0; ko < KC; ++ko) acc[ko] = 0.f;
#pragma unroll
    for (int kh = 0; kh < 3; ++kh)
#pragma unroll
        for (int kw = 0; kw < 3; ++kw) {
            // comp patch coords: row = (2(hd0+lhd)+kh-1) - R0 = 2*lhd+kh, etc.
            float4 rv = *reinterpret_cast<const float4*>(
                &comp_lds[cidx(2 * lhd + kh, 2 * lwd + kw, cig * 4)]);
#pragma unroll
            for (int cii = 0; cii < 4; ++cii) {
                float cv = (&rv.x)[cii];
                int   ci = cig * 4 + cii;           // wave-uniform
#pragma unroll
                for (int ko = 0; ko < KC; ++ko)
                    acc[ko] = fmaf(cv, we[((ko * CM + ci) * 3 + kh) * 3 + kw], acc[ko]);
            }
        }
#pragma unroll
    for (int ko = 0; ko < KC; ++ko) part[cig][ko][o] = acc[ko];
    __syncthreads();

    // ---- pass 3: reduce + softmax + store ----
    if (threadIdx.x < 64) {
        float a[KC];
#pragma unroll
        for (int ko = 0; ko < KC; ++ko)
            a[ko] = (part[0][ko][o] + part[1][ko][o]) +
                    (part[2][ko][o] + part[3][ko][o]);
        float m = a[0];
#pragma unroll
        for (int ko = 1; ko < KC; ++ko) m = fmaxf(m, a[ko]);
        float s = 0.f;
#pragma unroll
        for (int ko = 0; ko < KC; ++ko) { a[ko] = __expf(a[ko] - m); s += a[ko]; }
        float inv = 1.f / s;
        float* kp = ker + (size_t)b * KC * HWD + (hd0 + lhd) * WD + (wd0 + lwd);
#pragma unroll
        for (int ko = 0; ko < KC; ++ko) kp[ko * HWD] = a[ko] * inv;
    }
}

// ---- stage 3: 5x5 s2 reassembly (unchanged from the 96.3 us round) ----
#define CH  2
__global__ __launch_bounds__(128) void reassemble_k(const float* __restrict__ x,
                                                    const float* __restrict__ ker,
                                                    float* __restrict__ out) {
    int bid  = blockIdx.x;
    int r_   = bid & 7;
    int t_   = bid >> 3;
    int cgrp = t_ & 63;                             // 0..63 (2 channels each)
    int s_   = t_ >> 6;                             // 0..24
    int v_   = s_ * 8 + r_;                         // 0..199
    int b    = v_ / 25;
    int pblk = v_ % 25;

    int pix = pblk * 128 + threadIdx.x;             // 0..3199
    int hd  = pix / 40;
    int pr  = pix % 40;
    int wd0 = pr * 2;

    const float* kb = ker + (size_t)b * KC * HWD + hd * WD + wd0;
    float k0m[KC], k1m[KC];
    bool rv[5];
#pragma unroll
    for (int i = 0; i < 5; ++i) rv[i] = (unsigned)(2 * hd + i - 2) < H;
    bool c0lo = (pr > 0);
    bool c1hi = (pr < 39);
#pragma unroll
    for (int i = 0; i < 5; ++i)
#pragma unroll
        for (int j = 0; j < 5; ++j) {
            float2 kv = *reinterpret_cast<const float2*>(kb + (i * 5 + j) * HWD);
            k0m[i * 5 + j] = (rv[i] && (j >= 2 || c0lo)) ? kv.x : 0.f;
            k1m[i * 5 + j] = (rv[i] && (j <= 3 || c1hi)) ? kv.y : 0.f;
        }

    int offA[5], offB[5], offC[5];
#pragma unroll
    for (int i = 0; i < 5; ++i) {
        int rc = min(max(2 * hd + i - 2, 0), H - 1);
        int ro = rc * W + 4 * pr;
        offA[i] = max(ro - 2, 0);
        offB[i] = ro;
        offC[i] = min(ro + 4, HW - 1);
    }

    const float* xc = x + (size_t)(b * C + cgrp * CH) * HW;
    float* ob = out + ((size_t)(b * C + cgrp * CH) * HD + hd) * WD + wd0;
#pragma unroll
    for (int c8 = 0; c8 < CH; ++c8) {
        float acc0 = 0.f, acc1 = 0.f;
#pragma unroll
        for (int i = 0; i < 5; ++i) {
            float2 a  = *reinterpret_cast<const float2*>(xc + offA[i]);
            float4 bq = *reinterpret_cast<const float4*>(xc + offB[i]);
            float  cs = xc[offC[i]];
            acc0 = fmaf(a.x,  k0m[i * 5 + 0], acc0);
            acc0 = fmaf(a.y,  k0m[i * 5 + 1], acc0);
            acc0 = fmaf(bq.x, k0m[i * 5 + 2], acc0);
            acc0 = fmaf(bq.y, k0m[i * 5 + 3], acc0);
            acc0 = fmaf(bq.z, k0m[i * 5 + 4], acc0);
            acc1 = fmaf(bq.x, k1m[i * 5 + 0], acc1);
            acc1 = fmaf(bq.y, k1m[i * 5 + 1], acc1);
            acc1 = fmaf(bq.z, k1m[i * 5 + 2], acc1);
            acc1 = fmaf(bq.w, k1m[i * 5 + 3], acc1);
            acc1 = fmaf(cs,   k1m[i * 5 + 4], acc1);
        }
        *reinterpret_cast<float2*>(ob) = make_float2(acc0, acc1);
        xc += HW;
        ob += HWD;
    }
}

extern "C" void kernel_launch(void* const* d_in, const int* in_sizes, int n_in,
                              void* d_out, int out_size, void* d_ws, size_t ws_size,
                              hipStream_t stream) {
    const float* x  = (const float*)d_in[0];
    const float* wc = (const float*)d_in[1];
    const float* we = (const float*)d_in[2];
    float* out = (float*)d_out;
    float* ker = (float*)d_ws;                      // B*KC*HWD = 1,280,000 f32

    encode_fused_k<<<B * 10 * 10, 256, 0, stream>>>(x, wc, we, ker);     // 800 blocks
    reassemble_k  <<<B * 64 * 25, 128, 0, stream>>>(x, ker, out);        // 12800 blocks
}

// Round 7
// 149.684 us; speedup vs baseline: 1.7582x; 1.7582x over previous
//
#include <hip/hip_runtime.h>

// CARAFE++ downsample: B=8, C=128, H=W=160, stride 2 -> HD=WD=80
// *** MEASUREMENT ROUND: kernels are the 96.3us R4 versions, with work
// repeated inside each dispatch (compress x3, reassemble x2, idempotent
// identical writes) so each surfaces above the harness's ~59us fill
// dispatches in the rocprof top-5 with full counter rows. ***
#define B   8
#define C   128
#define H   160
#define W   160
#define HW  (H*W)       // 25600
#define CM  16
#define KC  25
#define HD  80
#define WD  80
#define HWD (HD*WD)     // 6400
#define CH  2           // channels per reassemble thread

// ---- stage 1: 1x1 conv 128->16, 2 pixels/thread, ci unrolled x16 ----
__global__ __launch_bounds__(256) void compress_k(const float* __restrict__ x,
                                                  const float* __restrict__ wc,
                                                  float* __restrict__ comp) {
    int gid = blockIdx.x * 256 + threadIdx.x;       // 0 .. B*HW/2-1
    int b   = gid / (HW / 2);
    int pos = (gid % (HW / 2)) * 2;
    const float* xb = x + (size_t)b * C * HW + pos;
    for (int rep = 0; rep < 3; ++rep) {             // x3 work, idempotent
        float2 acc[CM];
#pragma unroll
        for (int co = 0; co < CM; ++co) acc[co] = make_float2(0.f, 0.f);
        for (int ci0 = 0; ci0 < C; ci0 += 16) {
            float2 v[16];
#pragma unroll
            for (int u = 0; u < 16; ++u)            // 16 loads in flight
                v[u] = *reinterpret_cast<const float2*>(xb + (size_t)(ci0 + u) * HW);
#pragma unroll
            for (int u = 0; u < 16; ++u)
#pragma unroll
                for (int co = 0; co < CM; ++co) {
                    float wv = wc[co * C + ci0 + u];    // uniform -> s_load
                    acc[co].x = fmaf(v[u].x, wv, acc[co].x);
                    acc[co].y = fmaf(v[u].y, wv, acc[co].y);
                }
        }
#pragma unroll
        for (int co = 0; co < CM; ++co)
            asm volatile("" : "+v"(acc[co].x), "+v"(acc[co].y));  // no DSE across reps
        float* cb = comp + (size_t)b * CM * HW + pos;
#pragma unroll
        for (int co = 0; co < CM; ++co)
            *reinterpret_cast<float2*>(cb + co * HW) = acc[co];
    }
}

// ---- stage 2: 3x3 s2 conv 16->25 + softmax; ci split across 4 waves ----
__global__ __launch_bounds__(256) void encoder_k(const float* __restrict__ comp,
                                                 const float* __restrict__ we,
                                                 float* __restrict__ ker) {
    __shared__ float part[4][KC][64];
    int lane = threadIdx.x & 63;
    int sub  = __builtin_amdgcn_readfirstlane(threadIdx.x >> 6);  // wave id, uniform
    int p  = blockIdx.x * 64 + lane;                // pixel 0..51199
    int b  = p / HWD;
    int r2 = p % HWD;
    int hd = r2 / WD;
    int wd = r2 % WD;
    const float* cb = comp + (size_t)b * CM * HW;
    float acc[KC];
#pragma unroll
    for (int ko = 0; ko < KC; ++ko) acc[ko] = 0.f;
#pragma unroll
    for (int cii = 0; cii < 4; ++cii) {
        int ci = sub * 4 + cii;                     // uniform -> we stays s_load
#pragma unroll
        for (int kh = 0; kh < 3; ++kh) {
            int r    = 2 * hd + kh - 1;
            bool rok = (unsigned)r < H;
            int rc   = min(max(r, 0), H - 1);
#pragma unroll
            for (int kw = 0; kw < 3; ++kw) {
                int c0  = 2 * wd + kw - 1;
                bool ok = rok && ((unsigned)c0 < W);
                int cc  = min(max(c0, 0), W - 1);
                float cv = cb[(size_t)ci * HW + rc * W + cc];
                cv = ok ? cv : 0.f;
#pragma unroll
                for (int ko = 0; ko < KC; ++ko)
                    acc[ko] = fmaf(cv, we[((ko * CM + ci) * 3 + kh) * 3 + kw], acc[ko]);
            }
        }
    }
#pragma unroll
    for (int ko = 0; ko < KC; ++ko) part[sub][ko][lane] = acc[ko];
    __syncthreads();
    if (threadIdx.x < 64) {
        float a[KC];
#pragma unroll
        for (int ko = 0; ko < KC; ++ko)
            a[ko] = (part[0][ko][lane] + part[1][ko][lane]) +
                    (part[2][ko][lane] + part[3][ko][lane]);
        float m = a[0];
#pragma unroll
        for (int ko = 1; ko < KC; ++ko) m = fmaxf(m, a[ko]);
        float s = 0.f;
#pragma unroll
        for (int ko = 0; ko < KC; ++ko) { a[ko] = __expf(a[ko] - m); s += a[ko]; }
        float inv = 1.f / s;
        float* kp = ker + (size_t)b * KC * HWD + hd * WD + wd;
#pragma unroll
        for (int ko = 0; ko < KC; ++ko) kp[ko * HWD] = a[ko] * inv;
    }
}

// ---- stage 3: 5x5 s2 reassembly; wd-pair x 2 channels per thread ----
__global__ __launch_bounds__(128) void reassemble_k(const float* __restrict__ x,
                                                    const float* __restrict__ ker,
                                                    float* __restrict__ out) {
    // bid = (s*64 + cgrp)*8 + r, where v = b*25 + pblk, r = v%8, s = v/8
    int bid  = blockIdx.x;
    int r_   = bid & 7;
    int t_   = bid >> 3;
    int cgrp = t_ & 63;                             // 0..63 (2 channels each)
    int s_   = t_ >> 6;                             // 0..24
    int v_   = s_ * 8 + r_;                         // 0..199
    int b    = v_ / 25;
    int pblk = v_ % 25;

    int pix = pblk * 128 + threadIdx.x;             // 0..3199
    int hd  = pix / 40;
    int pr  = pix % 40;
    int wd0 = pr * 2;                               // output cols (wd0, wd0+1)

    for (int rep = 0; rep < 2; ++rep) {             // x2 work, idempotent
        const float* kb = ker + (size_t)b * KC * HWD + hd * WD + wd0;
        float k0m[KC], k1m[KC];
        bool rv[5];
#pragma unroll
        for (int i = 0; i < 5; ++i) rv[i] = (unsigned)(2 * hd + i - 2) < H;
        bool c0lo = (pr > 0);
        bool c1hi = (pr < 39);
#pragma unroll
        for (int i = 0; i < 5; ++i)
#pragma unroll
            for (int j = 0; j < 5; ++j) {
                float2 kv = *reinterpret_cast<const float2*>(kb + (i * 5 + j) * HWD);
                k0m[i * 5 + j] = (rv[i] && (j >= 2 || c0lo)) ? kv.x : 0.f;
                k1m[i * 5 + j] = (rv[i] && (j <= 3 || c1hi)) ? kv.y : 0.f;
            }

        int offA[5], offB[5], offC[5];
#pragma unroll
        for (int i = 0; i < 5; ++i) {
            int rc = min(max(2 * hd + i - 2, 0), H - 1);
            int ro = rc * W + 4 * pr;
            offA[i] = max(ro - 2, 0);
            offB[i] = ro;
            offC[i] = min(ro + 4, HW - 1);
        }

        const float* xc = x + (size_t)(b * C + cgrp * CH) * HW;
        float* ob = out + ((size_t)(b * C + cgrp * CH) * HD + hd) * WD + wd0;
#pragma unroll
        for (int c8 = 0; c8 < CH; ++c8) {
            float acc0 = 0.f, acc1 = 0.f;
#pragma unroll
            for (int i = 0; i < 5; ++i) {
                float2 a  = *reinterpret_cast<const float2*>(xc + offA[i]);
                float4 bq = *reinterpret_cast<const float4*>(xc + offB[i]);
                float  cs = xc[offC[i]];
                acc0 = fmaf(a.x,  k0m[i * 5 + 0], acc0);
                acc0 = fmaf(a.y,  k0m[i * 5 + 1], acc0);
                acc0 = fmaf(bq.x, k0m[i * 5 + 2], acc0);
                acc0 = fmaf(bq.y, k0m[i * 5 + 3], acc0);
                acc0 = fmaf(bq.z, k0m[i * 5 + 4], acc0);
                acc1 = fmaf(bq.x, k1m[i * 5 + 0], acc1);
                acc1 = fmaf(bq.y, k1m[i * 5 + 1], acc1);
                acc1 = fmaf(bq.z, k1m[i * 5 + 2], acc1);
                acc1 = fmaf(bq.w, k1m[i * 5 + 3], acc1);
                acc1 = fmaf(cs,   k1m[i * 5 + 4], acc1);
            }
            asm volatile("" : "+v"(acc0), "+v"(acc1));   // no DSE across reps
            *reinterpret_cast<float2*>(ob) = make_float2(acc0, acc1);
            xc += HW;
            ob += HWD;
        }
    }
}

extern "C" void kernel_launch(void* const* d_in, const int* in_sizes, int n_in,
                              void* d_out, int out_size, void* d_ws, size_t ws_size,
                              hipStream_t stream) {
    const float* x  = (const float*)d_in[0];
    const float* wc = (const float*)d_in[1];
    const float* we = (const float*)d_in[2];
    float* out  = (float*)d_out;
    float* comp = (float*)d_ws;                       // B*CM*HW   = 3,276,800 f32
    float* ker  = comp + (size_t)B * CM * HW;         // B*KC*HWD  = 1,280,000 f32

    compress_k  <<<(B * HW / 2) / 256, 256, 0, stream>>>(x, wc, comp);   // 400 blocks
    encoder_k   <<<(B * HWD) / 64,     256, 0, stream>>>(comp, we, ker); // 800 blocks
    reassemble_k<<<B * 64 * 25,        128, 0, stream>>>(x, ker, out);   // 12800 blocks
}

// Round 8
// 115.465 us; speedup vs baseline: 2.2792x; 1.2964x over previous
//
#include <hip/hip_runtime.h>
#include <hip/hip_bf16.h>

// CARAFE++ downsample: B=8, C=128, H=W=160, stride 2 -> HD=WD=80
#define B   8
#define C   128
#define H   160
#define W   160
#define HW  (H*W)       // 25600
#define CM  16
#define KC  25
#define HD  80
#define WD  80
#define HWD (HD*WD)     // 6400
#define KP  28          // ker taps padded to float4 multiple (25 -> 28)
#define CH  4           // channels per reassemble thread

// ---- stage 1: 1x1 conv 128->16, ONE pixel/thread (800 blocks, 3200 waves),
//      bf16 comp output (halves comp traffic + ws footprint) ----
__global__ __launch_bounds__(256) void compress_k(const float* __restrict__ x,
                                                  const float* __restrict__ wc,
                                                  __hip_bfloat16* __restrict__ comp) {
    int gid = blockIdx.x * 256 + threadIdx.x;       // 0 .. B*HW-1
    int b   = gid / HW;
    int pos = gid % HW;
    const float* xb = x + (size_t)b * C * HW + pos;
    float acc[CM];
#pragma unroll
    for (int co = 0; co < CM; ++co) acc[co] = 0.f;
    for (int ci0 = 0; ci0 < C; ci0 += 16) {
        float v[16];
#pragma unroll
        for (int u = 0; u < 16; ++u)                // 16 loads in flight
            v[u] = xb[(size_t)(ci0 + u) * HW];
#pragma unroll
        for (int u = 0; u < 16; ++u)
#pragma unroll
            for (int co = 0; co < CM; ++co)
                acc[co] = fmaf(v[u], wc[co * C + ci0 + u], acc[co]);  // wc -> s_load
    }
    __hip_bfloat16* cb = comp + (size_t)b * CM * HW + pos;
#pragma unroll
    for (int co = 0; co < CM; ++co)
        cb[co * HW] = __float2bfloat16(acc[co]);
}

// ---- stage 2: 3x3 s2 conv 16->25 + softmax; ci split across 4 waves.
//      Output ker_t layout: [global_pixel][KP] (pixel-major, padded),
//      stored coalesced via LDS transpose. ----
__global__ __launch_bounds__(256) void encoder_k(const __hip_bfloat16* __restrict__ comp,
                                                 const float* __restrict__ we,
                                                 float* __restrict__ ker_t) {
    __shared__ float part[4][KC][65];               // 65: bank-spread for transpose read
    int lane = threadIdx.x & 63;
    int sub  = __builtin_amdgcn_readfirstlane(threadIdx.x >> 6);  // wave id, uniform
    int p  = blockIdx.x * 64 + lane;                // global pixel 0..51199
    int b  = p / HWD;
    int r2 = p % HWD;
    int hd = r2 / WD;
    int wd = r2 % WD;
    const __hip_bfloat16* cb = comp + (size_t)b * CM * HW;
    float acc[KC];
#pragma unroll
    for (int ko = 0; ko < KC; ++ko) acc[ko] = 0.f;
#pragma unroll
    for (int cii = 0; cii < 4; ++cii) {
        int ci = sub * 4 + cii;                     // uniform -> we stays s_load
#pragma unroll
        for (int kh = 0; kh < 3; ++kh) {
            int r    = 2 * hd + kh - 1;
            bool rok = (unsigned)r < H;
            int rc   = min(max(r, 0), H - 1);
#pragma unroll
            for (int kw = 0; kw < 3; ++kw) {
                int c0  = 2 * wd + kw - 1;
                bool ok = rok && ((unsigned)c0 < W);
                int cc  = min(max(c0, 0), W - 1);
                float cv = __bfloat162float(cb[(size_t)ci * HW + rc * W + cc]);
                cv = ok ? cv : 0.f;
#pragma unroll
                for (int ko = 0; ko < KC; ++ko)
                    acc[ko] = fmaf(cv, we[((ko * CM + ci) * 3 + kh) * 3 + kw], acc[ko]);
            }
        }
    }
#pragma unroll
    for (int ko = 0; ko < KC; ++ko) part[sub][ko][lane] = acc[ko];
    __syncthreads();
    if (threadIdx.x < 64) {
        float a[KC];
#pragma unroll
        for (int ko = 0; ko < KC; ++ko)
            a[ko] = (part[0][ko][lane] + part[1][ko][lane]) +
                    (part[2][ko][lane] + part[3][ko][lane]);
        float m = a[0];
#pragma unroll
        for (int ko = 1; ko < KC; ++ko) m = fmaxf(m, a[ko]);
        float s = 0.f;
#pragma unroll
        for (int ko = 0; ko < KC; ++ko) { a[ko] = __expf(a[ko] - m); s += a[ko]; }
        float inv = 1.f / s;
#pragma unroll
        for (int ko = 0; ko < KC; ++ko) part[0][ko][lane] = a[ko] * inv;
    }
    __syncthreads();
    // cooperative transposed store: 64 pixels x KP floats, fully coalesced
    size_t base = (size_t)blockIdx.x * 64 * KP;
    for (int idx = threadIdx.x; idx < 64 * KP; idx += 256) {
        int pix = idx / KP, k = idx % KP;
        float v = (k < KC) ? part[0][k][pix] : 0.f;
        ker_t[base + idx] = v;
    }
}

// ---- stage 3: 5x5 s2 reassembly; wd-pair x 4 channels per thread.
//      ker prologue = 14 dense float4 loads from pixel-major ker_t. ----
__global__ __launch_bounds__(128) void reassemble_k(const float* __restrict__ x,
                                                    const float* __restrict__ ker_t,
                                                    float* __restrict__ out) {
    // bid = ((s*32 + cgrp)*8 + r), v = s*8+r = b*25+pblk  (XCD-aware spread)
    int bid  = blockIdx.x;
    int r_   = bid & 7;
    int t_   = bid >> 3;
    int cgrp = t_ & 31;                             // 0..31 (4 channels each)
    int s_   = t_ >> 5;                             // 0..24
    int v_   = s_ * 8 + r_;                         // 0..199
    int b    = v_ / 25;
    int pblk = v_ % 25;

    int pix = pblk * 128 + threadIdx.x;             // 0..3199
    int hd  = pix / 40;
    int pr  = pix % 40;
    int wd0 = pr * 2;                               // output cols (wd0, wd0+1)

    // masked kernel weights from pixel-major ker_t (dense float4 loads)
    size_t q0 = ((size_t)b * HWD + hd * WD + wd0) * KP;
    float k0m[KC], k1m[KC];
    bool rv[5];
#pragma unroll
    for (int i = 0; i < 5; ++i) rv[i] = (unsigned)(2 * hd + i - 2) < H;
    bool c0lo = (pr > 0);                           // out0 taps j=0,1 valid?
    bool c1hi = (pr < 39);                          // out1 tap  j=4  valid?
#pragma unroll
    for (int t = 0; t < 7; ++t) {
        float4 a0 = *reinterpret_cast<const float4*>(ker_t + q0 + 4 * t);
        float4 a1 = *reinterpret_cast<const float4*>(ker_t + q0 + KP + 4 * t);
#pragma unroll
        for (int e = 0; e < 4; ++e) {
            int tap = 4 * t + e;
            if (tap < KC) {
                int i = tap / 5, j = tap % 5;
                float v0 = (&a0.x)[e], v1 = (&a1.x)[e];
                k0m[tap] = (rv[i] && (j >= 2 || c0lo)) ? v0 : 0.f;
                k1m[tap] = (rv[i] && (j <= 3 || c1hi)) ? v1 : 0.f;
            }
        }
    }

    // per-row window offsets, clamped in-bounds (clamped taps are zero-masked)
    int offA[5], offB[5], offC[5];
#pragma unroll
    for (int i = 0; i < 5; ++i) {
        int rc = min(max(2 * hd + i - 2, 0), H - 1);
        int ro = rc * W + 4 * pr;
        offA[i] = max(ro - 2, 0);                   // cols 4pr-2,4pr-1 (8B aligned)
        offB[i] = ro;                               // cols 4pr..4pr+3 (16B aligned)
        offC[i] = min(ro + 4, HW - 1);              // col  4pr+4
    }

    const float* xc = x + (size_t)(b * C + cgrp * CH) * HW;   // block-uniform base
    float* ob = out + ((size_t)(b * C + cgrp * CH) * HD + hd) * WD + wd0;
#pragma unroll
    for (int c8 = 0; c8 < CH; ++c8) {
        float acc0 = 0.f, acc1 = 0.f;
#pragma unroll
        for (int i = 0; i < 5; ++i) {
            float2 a  = *reinterpret_cast<const float2*>(xc + offA[i]);
            float4 bq = *reinterpret_cast<const float4*>(xc + offB[i]);
            float  cs = xc[offC[i]];
            acc0 = fmaf(a.x,  k0m[i * 5 + 0], acc0);
            acc0 = fmaf(a.y,  k0m[i * 5 + 1], acc0);
            acc0 = fmaf(bq.x, k0m[i * 5 + 2], acc0);
            acc0 = fmaf(bq.y, k0m[i * 5 + 3], acc0);
            acc0 = fmaf(bq.z, k0m[i * 5 + 4], acc0);
            acc1 = fmaf(bq.x, k1m[i * 5 + 0], acc1);
            acc1 = fmaf(bq.y, k1m[i * 5 + 1], acc1);
            acc1 = fmaf(bq.z, k1m[i * 5 + 2], acc1);
            acc1 = fmaf(bq.w, k1m[i * 5 + 3], acc1);
            acc1 = fmaf(cs,   k1m[i * 5 + 4], acc1);
        }
        *reinterpret_cast<float2*>(ob) = make_float2(acc0, acc1);
        xc += HW;
        ob += HWD;
    }
}

extern "C" void kernel_launch(void* const* d_in, const int* in_sizes, int n_in,
                              void* d_out, int out_size, void* d_ws, size_t ws_size,
                              hipStream_t stream) {
    const float* x  = (const float*)d_in[0];
    const float* wc = (const float*)d_in[1];
    const float* we = (const float*)d_in[2];
    float* out = (float*)d_out;
    __hip_bfloat16* comp = (__hip_bfloat16*)d_ws;         // B*CM*HW bf16 = 6.55 MB
    float* ker_t = (float*)((char*)d_ws + (size_t)B * CM * HW * sizeof(__hip_bfloat16));
                                                          // B*HWD*KP f32 = 5.73 MB

    compress_k  <<<(B * HW) / 256,  256, 0, stream>>>(x, wc, comp);      // 800 blocks
    encoder_k   <<<(B * HWD) / 64,  256, 0, stream>>>(comp, we, ker_t);  // 800 blocks
    reassemble_k<<<B * 32 * 25,     128, 0, stream>>>(x, ker_t, out);    // 6400 blocks
}